// Round 16
// baseline (154.172 us; speedup 1.0000x reference)
//
#include <hip/hip_runtime.h>
#include <hip/hip_bf16.h>

#define B_ 8
#define S_ 1024
#define U_ 1024
#define H_ 16
#define DK_ 64

typedef __attribute__((ext_vector_type(8))) short short8;
typedef __attribute__((ext_vector_type(4))) float f32x4;
typedef __attribute__((ext_vector_type(16))) float f32x16;

__device__ inline ushort f2b(float x) {
  union { float f; unsigned u; } v; v.f = x;
  unsigned r = (v.u + 0x7FFFu + ((v.u >> 16) & 1u)) >> 16;
  return (ushort)r;
}
__device__ inline unsigned cvtpk(float lo, float hi) {
  unsigned r;
  asm("v_cvt_pk_bf16_f32 %0, %1, %2" : "=v"(r) : "v"(lo), "v"(hi));
  return r;
}

__device__ inline void gld16(const ushort* g, ushort* l) {
  __builtin_amdgcn_global_load_lds((__attribute__((address_space(1))) void*)(g),
                                   (__attribute__((address_space(3))) void*)(l),
                                   16, 0, 0);
}

// ------------- fused pack: query fp32->bf16 + weight transpose ---------------
__global__ __launch_bounds__(256) void pack_all_kern(
    const float* __restrict__ X, ushort* __restrict__ Xb,
    const float* __restrict__ Wq, const float* __restrict__ Wk, const float* __restrict__ Wv,
    const float* __restrict__ bq, const float* __restrict__ bk, const float* __restrict__ bv,
    const float* __restrict__ Wo,
    ushort* __restrict__ Wqkv, float* __restrict__ Bqkv, ushort* __restrict__ Wob)
{
  __shared__ ushort tile[64*65];
  const int t = threadIdx.x;
  if (blockIdx.x < 4096) {
    int idx = blockIdx.x * 256 + t;
    const float4* src = (const float4*)X + (size_t)idx * 2;
    float4 a = src[0], b = src[1];
    ushort r[8];
    r[0]=f2b(a.x); r[1]=f2b(a.y); r[2]=f2b(a.z); r[3]=f2b(a.w);
    r[4]=f2b(b.x); r[5]=f2b(b.y); r[6]=f2b(b.z); r[7]=f2b(b.w);
    *(uint4*)(Xb + (size_t)idx*8) = *(uint4*)r;
    return;
  }
  const int bid = blockIdx.x - 4096;
  if (bid < 768) {
    int p = bid >> 8, rem = bid & 255;
    int h = rem >> 4, kc = rem & 15, k0 = kc*64;
    const float* Wsrc = (p==0) ? Wq : ((p==1) ? Wk : Wv);
    #pragma unroll
    for (int i = 0; i < 16; ++i) {
      int e = t + i*256;
      int r = e >> 6, d = e & 63;
      tile[d*65 + r] = f2b(Wsrc[h*65536 + (k0+r)*64 + d]);
    }
    __syncthreads();
    #pragma unroll
    for (int i = 0; i < 16; ++i) {
      int e = t + i*256;
      int d = e >> 6, r = e & 63;
      Wqkv[(size_t)(p*1024 + h*64 + d)*1024 + k0 + r] = tile[d*65 + r];
    }
    if (kc == 0 && t < 64) {
      const float* bsrc = (p==0) ? bq : ((p==1) ? bk : bv);
      Bqkv[p*1024 + h*64 + t] = bsrc[h*64 + t];
    }
  } else {
    int b2 = bid - 768;
    int nc = b2 >> 4, kc = b2 & 15;
    int n0 = nc*64, k0 = kc*64;
    #pragma unroll
    for (int i = 0; i < 16; ++i) {
      int e = t + i*256;
      int r = e >> 6, d = e & 63;
      tile[d*65 + r] = f2b(Wo[(size_t)(k0+r)*1024 + n0 + d]);
    }
    __syncthreads();
    #pragma unroll
    for (int i = 0; i < 16; ++i) {
      int e = t + i*256;
      int d = e >> 6, r = e & 63;
      Wob[(size_t)(n0+d)*1024 + k0 + r] = tile[d*65 + r];
    }
  }
}

// ---- QKV GEMM: 256x256x64, 8-phase counted-vmcnt pipeline (T2+T3+T4+T5) ----
// 512 thr = 8 waves (2M x 4N), per-wave C = 128x64. LDS 128 KB = 2 dbuf x
// (A-unit[qm0],A-unit[qm1],B-unit[qn0],B-unit[qn1]) each 16 KB, phase-unit
// layout: A[qm][wr][64][64], B[qn][wc][32][64]. Per phase: vmcnt(8) ->
// s_barrier -> 12 ds_read -> stage 1 unit (2 gld_lds) -> lgkmcnt(0) ->
// 16 MFMA. Race ledger: stage at phase p targets the chunk last-read at
// phase p-1 (entry barrier => all waves executed p-1's lgkmcnt(0) => reads
// retired). vmcnt(8) = 4 units in flight; covers every consume deadline
// given the 6-unit prologue (count-verified). Never vmcnt(0) in loop.
// XOR-chunk swizzle both-sides (rule #21).
__global__ __launch_bounds__(512, 2) void gemmw8_kern(
    const ushort* __restrict__ A,
    const ushort* __restrict__ Bw,
    const float* __restrict__ bias,
    ushort* __restrict__ Qb, ushort* __restrict__ Kb, ushort* __restrict__ Vtb)
{
  __shared__ __align__(16) ushort As[2][2][8192];   // [dbuf][qm][unit 128x64]
  __shared__ __align__(16) ushort Bs[2][2][8192];   // [dbuf][qn][unit 128x64]

  const int t = threadIdx.x;
  const int l = t & 63, w = t >> 6;
  const int wr = w >> 2, wc = w & 3;
  const int li = l & 15, c4 = l >> 4;

  // raster: 384 blocks = 32m x 12n; XCD chunk 48 = 4m x 12n (bijective)
  const int swz = (blockIdx.x & 7) * 48 + (blockIdx.x >> 3);
  const int ms = swz / 48, rem = swz % 48;
  const int m0 = (ms*4 + (rem & 3)) * 256;
  const int n0 = (rem >> 2) * 256;

  f32x4 acc[8][4];
  #pragma unroll
  for (int i=0;i<8;i++)
    #pragma unroll
    for (int j=0;j<4;j++) acc[i][j] = (f32x4)0.0f;

  // stage one 16 KB unit (1024 chunks of 16B, 2/thread); LDS dest linear,
  // source column chunk XOR-permuted (both-sides with the ds_read swizzle)
  auto SGA = [&](int buf, int qm, int kk) {
    #pragma unroll
    for (int u=0;u<2;++u) {
      int n = u*512 + t;
      int r = n >> 3, jj = (n & 7) ^ (r & 7);
      gld16(&A[(size_t)(m0 + (r>>6)*128 + qm*64 + (r&63))*1024 + kk + jj*8],
            &As[buf][qm][n*8]);
    }
  };
  auto SGB = [&](int buf, int qn, int kk) {
    #pragma unroll
    for (int u=0;u<2;++u) {
      int n = u*512 + t;
      int r = n >> 3, jj = (n & 7) ^ (r & 7);
      gld16(&Bw[(size_t)(n0 + (r>>5)*64 + qn*32 + (r&31))*1024 + kk + jj*8],
            &Bs[buf][qn][n*8]);
    }
  };

  // prologue: 6 units in steady-state issue order (12 loads)
  SGB(0,0,0); SGA(0,0,0); SGA(0,1,0); SGB(0,1,0); SGB(1,0,64); SGA(1,0,64);

#define PH(BUF, QM, QN, STAGE_STMT)                                           \
  asm volatile("s_waitcnt vmcnt(8)" ::: "memory");                            \
  __builtin_amdgcn_s_barrier();                                               \
  __builtin_amdgcn_sched_barrier(0);                                          \
  {                                                                           \
    short8 af[4][2], bf[2][2];                                                \
    _Pragma("unroll")                                                         \
    for (int i=0;i<4;i++) {                                                   \
      int ar = wr*64 + i*16 + li;                                             \
      _Pragma("unroll")                                                       \
      for (int ks=0;ks<2;ks++)                                                \
        af[i][ks] = *(const short8*)&As[BUF][QM][ar*64 + (((ks*4+c4)^(li&7))*8)]; \
    }                                                                         \
    _Pragma("unroll")                                                         \
    for (int jj=0;jj<2;jj++) {                                                \
      int br = wc*32 + jj*16 + li;                                            \
      _Pragma("unroll")                                                       \
      for (int ks=0;ks<2;ks++)                                                \
        bf[jj][ks] = *(const short8*)&Bs[BUF][QN][br*64 + (((ks*4+c4)^(li&7))*8)]; \
    }                                                                         \
    STAGE_STMT;                                                               \
    asm volatile("s_waitcnt lgkmcnt(0)" ::: "memory");                        \
    __builtin_amdgcn_sched_barrier(0);                                        \
    __builtin_amdgcn_s_setprio(1);                                            \
    _Pragma("unroll")                                                         \
    for (int i=0;i<4;i++)                                                     \
      _Pragma("unroll")                                                       \
      for (int jj=0;jj<2;jj++)                                                \
        _Pragma("unroll")                                                     \
        for (int ks=0;ks<2;ks++)                                              \
          acc[(QM)*4+i][(QN)*2+jj] = __builtin_amdgcn_mfma_f32_16x16x32_bf16( \
              af[i][ks], bf[jj][ks], acc[(QM)*4+i][(QN)*2+jj], 0,0,0);        \
    __builtin_amdgcn_s_setprio(0);                                            \
  }

  #pragma unroll 1
  for (int it = 0; it < 8; ++it) {
    const int k1 = (2*it+1)*64;
    const int k2 = (2*it+2 < 16) ? (2*it+2)*64 : 0;   // dummy wrap on tail
    const int k3 = (2*it+3 < 16) ? (2*it+3)*64 : 0;
    PH(0,0,0, SGA(1,1,k1))
    PH(0,1,0, SGB(1,1,k1))
    PH(0,0,1, SGB(0,0,k2))
    PH(0,1,1, SGA(0,0,k2))
    PH(1,0,0, SGA(0,1,k2))
    PH(1,1,0, SGB(0,1,k2))
    PH(1,0,1, SGB(1,0,k3))
    PH(1,1,1, SGA(1,0,k3))
  }
#undef PH

  #pragma unroll
  for (int i=0;i<8;i++) {
    int rbase = m0 + wr*128 + i*16 + c4*4;
    #pragma unroll
    for (int j=0;j<4;j++) {
      int col = n0 + wc*64 + j*16 + li;
      float bv = bias[col];
      int p = col >> 10, h = (col >> 6) & 15, d = col & 63;
      int b = rbase >> 10, s = rbase & 1023;
      if (p == 2) {            // V -> transposed [bh][d][s], 8B packed store
        unsigned pk4[2];
        pk4[0] = cvtpk(acc[i][j][0] + bv, acc[i][j][1] + bv);
        pk4[1] = cvtpk(acc[i][j][2] + bv, acc[i][j][3] + bv);
        *(uint2*)&Vtb[((size_t)((b*16+h)*64 + d))*1024 + s] = *(uint2*)pk4;
      } else {
        ushort* dst = (p==0) ? Qb : Kb;
        float sc = (p==0) ? 0.18033688011112042f : 1.0f;   // 0.125*log2(e)
        #pragma unroll
        for (int r=0;r<4;r++)
          dst[(((size_t)(b*16 + h))*1024 + s + r)*64 + d] = f2b((acc[i][j][r] + bv) * sc);
      }
    }
  }
}

// ---- out-proj GEMM: 128x128x32 triple buffer (frozen) ----------------------
template<int MODE>
__global__ __launch_bounds__(256, 3) void gemm128_kern(
    const ushort* __restrict__ A,
    const ushort* __restrict__ Bw,
    const float* __restrict__ bias,
    ushort* __restrict__ Qb, ushort* __restrict__ Kb, ushort* __restrict__ Vtb,
    float* __restrict__ outF)
{
  __shared__ __align__(16) ushort As[3][4096];
  __shared__ __align__(16) ushort Bs[3][4096];

  const int t = threadIdx.x;
  const int l = t & 63, w = t >> 6;
  const int wr = w >> 1, wc = w & 1;
  const int li = l & 15, c4 = l >> 4;

  int m0, n0;
  {
    int swz = (blockIdx.x & 7) * 64 + (blockIdx.x >> 3);
    int ms = swz / 64, rem = swz % 64;
    m0 = (ms*8 + (rem & 7)) * 128;  n0 = (rem >> 3) * 128;
  }

  f32x4 acc[4][4];
  #pragma unroll
  for (int i=0;i<4;i++)
    #pragma unroll
    for (int j=0;j<4;j++) acc[i][j] = (f32x4)0.0f;

  auto SA = [&](int buf, int kk) {
    #pragma unroll
    for (int p2=0;p2<2;++p2) {
      int n = p2*256 + t;
      int row = n >> 2, jj = (n & 3) ^ ((row >> 1) & 3);
      gld16(&A[(size_t)(m0 + row)*1024 + kk + jj*8], &As[buf][n*8]);
    }
  };
  auto SB = [&](int buf, int kk) {
    #pragma unroll
    for (int p2=0;p2<2;++p2) {
      int n = p2*256 + t;
      int row = n >> 2, jj = (n & 3) ^ ((row >> 1) & 3);
      gld16(&Bw[(size_t)(n0 + row)*1024 + kk + jj*8], &Bs[buf][n*8]);
    }
  };

  SA(0, 0);  SB(0, 0);
  SA(1, 32); SB(1, 32);

  for (int kt = 0; kt < 32; ++kt) {
    const int cur = kt % 3;
    asm volatile("s_waitcnt vmcnt(4)" ::: "memory");
    __builtin_amdgcn_s_barrier();
    __builtin_amdgcn_sched_barrier(0);

    short8 af[4], bf[4];
    #pragma unroll
    for (int i=0;i<4;i++) {
      int rA = wr*64 + i*16 + li;
      int rB = wc*64 + i*16 + li;
      af[i] = *(const short8*)&As[cur][rA*32 + ((c4 ^ ((rA>>1)&3))*8)];
      bf[i] = *(const short8*)&Bs[cur][rB*32 + ((c4 ^ ((rB>>1)&3))*8)];
    }
    __builtin_amdgcn_s_barrier();
    __builtin_amdgcn_sched_barrier(0);
    const int nb = (kt + 2) % 3;
    const int kk2 = ((kt + 2) & 31) * 32;
    SA(nb, kk2); SB(nb, kk2);

    __builtin_amdgcn_s_setprio(1);
    #pragma unroll
    for (int i=0;i<4;i++)
      #pragma unroll
      for (int j=0;j<4;j++)
        acc[i][j] = __builtin_amdgcn_mfma_f32_16x16x32_bf16(af[i], bf[j], acc[i][j], 0,0,0);
    __builtin_amdgcn_s_setprio(0);
  }

  #pragma unroll
  for (int i=0;i<4;i++) {
    int rbase = m0 + wr*64 + i*16 + c4*4;
    #pragma unroll
    for (int j=0;j<4;j++) {
      int col = n0 + wc*64 + j*16 + li;
      float bv = bias[col];
      #pragma unroll
      for (int r=0;r<4;r++)
        outF[(size_t)(rbase+r)*1024 + col] = acc[i][j][r] + bv;
    }
  }
}

// ------- causal flash attention: block-staged K/V + cvt_pk/max3 (frozen) ----
__global__ __launch_bounds__(256, 2) void attn_kern(
    const ushort* __restrict__ Qb, const ushort* __restrict__ Kb,
    const ushort* __restrict__ Vt, ushort* __restrict__ Ob)
{
  __shared__ __align__(16) ushort Ks[2][32*68];   // [s][d] stride 68
  __shared__ __align__(16) ushort Vs[2][64*44];   // [dv][s32] stride 44
  __shared__ __align__(16) ushort Pb[4][32*40];   // per-wave P [q][kv]
  __shared__ __align__(16) ushort OT[4][32*72];   // per-wave epilogue transpose
  const int t = threadIdx.x, l = t & 63, w = t >> 6;
  const int bid = blockIdx.x;
  const int x = bid & 7, i0 = bid >> 3;
  const int bh = x*16 + (i0 >> 2);                // bh clustered per XCD
  const int g  = i0 & 3;
  const int p  = g*4 + w;
  const int qta = p, qtb = 31 - p;
  const int NT = 32 - g*4;                        // block-uniform tile count

  const int col = l & 31, hi = l >> 5;
  const ushort* Qp = Qb + (size_t)bh*65536;
  const ushort* Kp = Kb + (size_t)bh*65536;
  const ushort* Vp = Vt + (size_t)bh*65536;

  const int ks_row = t >> 3, ks_c = t & 7;
  const int vs_row = t >> 2, vs_c = t & 3;

  short8 qfa[4], qfb[4];
  #pragma unroll
  for (int m=0;m<4;m++) {
    qfa[m] = *(const short8*)&Qp[(size_t)(qta*32+col)*64 + m*16 + hi*8];
    qfb[m] = *(const short8*)&Qp[(size_t)(qtb*32+col)*64 + m*16 + hi*8];
  }

  f32x16 aA0 = (f32x16)0.0f, aA1 = (f32x16)0.0f;
  f32x16 aB0 = (f32x16)0.0f, aB1 = (f32x16)0.0f;
  float mA = -1e30f, lA = 0.0f, mB = -1e30f, lB = 0.0f;
  ushort* Pw = &Pb[w][0];

  auto PROC = [&](f32x16& s, bool diag, float& mR, float& lS,
                  f32x16& o0, f32x16& o1, const short8* vf0, const short8* vf1) {
    if (diag) {
      #pragma unroll
      for (int r=0;r<16;r++) {
        int kvl = (r&3) + ((r>>2)<<3) + 4*hi;
        s[r] = (kvl > col) ? -1e9f : s[r];
      }
    }
    float t0 = fmaxf(fmaxf(s[0], s[1]), s[2]);
    float t1 = fmaxf(fmaxf(s[3], s[4]), s[5]);
    float t2 = fmaxf(fmaxf(s[6], s[7]), s[8]);
    float t3 = fmaxf(fmaxf(s[9], s[10]), s[11]);
    float t4 = fmaxf(fmaxf(s[12], s[13]), s[14]);
    float mx = fmaxf(fmaxf(fmaxf(t0, t1), t2), fmaxf(fmaxf(t3, t4), s[15]));
    mx = fmaxf(mx, __shfl_xor(mx, 32));
    if (__any(mx - mR > 8.0f)) {          // T13 defer-max (log2 units)
      float mN = fmaxf(mR, mx);
      float corr = __builtin_amdgcn_exp2f(mR - mN);
      mR = mN; lS *= corr;
      #pragma unroll
      for (int r=0;r<16;r++) { o0[r] *= corr; o1[r] *= corr; }
    }
    float pr[16];
    #pragma unroll
    for (int r=0;r<16;r++) pr[r] = __builtin_amdgcn_exp2f(s[r] - mR);
    float s8[8];
    #pragma unroll
    for (int r2=0;r2<8;r2++) s8[r2] = pr[2*r2] + pr[2*r2+1];
    #pragma unroll
    for (int r2=0;r2<4;r2++) s8[r2] += s8[r2+4];
    float rs = (s8[0]+s8[1]) + (s8[2]+s8[3]);
    rs += __shfl_xor(rs, 32);
    lS += rs;
    #pragma unroll
    for (int r2=0;r2<8;r2++) {
      int r = 2*r2;
      int kv = (r&3) + ((r>>2)<<3) + 4*hi;
      *(unsigned*)&Pw[col*40 + kv] = cvtpk(pr[r], pr[r+1]);
    }
    short8 pb0 = *(const short8*)&Pw[col*40 + hi*8];
    short8 pb1 = *(const short8*)&Pw[col*40 + 16 + hi*8];
    o0 = __builtin_amdgcn_mfma_f32_32x32x16_bf16(vf0[0], pb0, o0, 0,0,0);
    o0 = __builtin_amdgcn_mfma_f32_32x32x16_bf16(vf0[1], pb1, o0, 0,0,0);
    o1 = __builtin_amdgcn_mfma_f32_32x32x16_bf16(vf1[0], pb0, o1, 0,0,0);
    o1 = __builtin_amdgcn_mfma_f32_32x32x16_bf16(vf1[1], pb1, o1, 0,0,0);
  };

  { // stage tile 0 into buf 0
    uint4 k0v = *(const uint4*)&Kp[(size_t)ks_row*64 + ks_c*8];
    uint4 v0v = *(const uint4*)&Vp[(size_t)vs_row*1024 + vs_c*8];
    *(uint4*)&Ks[0][ks_row*68 + ks_c*8] = k0v;
    *(uint4*)&Vs[0][vs_row*44 + vs_c*8] = v0v;
  }
  __syncthreads();

  for (int kt = 0; kt < NT; ++kt) {
    const int cur = kt & 1;
    const bool pre = (kt + 1 < NT);
    uint4 kn2, vn2;
    if (pre) {   // T14: global prefetch of tile kt+1 (overlaps PROC below)
      kn2 = *(const uint4*)&Kp[(size_t)((kt+1)*32+ks_row)*64 + ks_c*8];
      vn2 = *(const uint4*)&Vp[(size_t)vs_row*1024 + (kt+1)*32 + vs_c*8];
    }

    short8 kf[4], vf0[2], vf1[2];
    #pragma unroll
    for (int m=0;m<4;m++)
      kf[m] = *(const short8*)&Ks[cur][col*68 + m*16 + hi*8];
    #pragma unroll
    for (int m=0;m<2;m++) {
      vf0[m] = *(const short8*)&Vs[cur][col*44 + m*16 + hi*8];
      vf1[m] = *(const short8*)&Vs[cur][(col+32)*44 + m*16 + hi*8];
    }

    const bool doB = (kt <= qtb), doA = (kt <= qta);
    if (doB) {
      f32x16 sB = (f32x16)0.0f;
      #pragma unroll
      for (int m=0;m<4;m++)
        sB = __builtin_amdgcn_mfma_f32_32x32x16_bf16(kf[m], qfb[m], sB, 0, 0, 0);
      if (doA) {
        f32x16 sA = (f32x16)0.0f;
        #pragma unroll
        for (int m=0;m<4;m++)
          sA = __builtin_amdgcn_mfma_f32_32x32x16_bf16(kf[m], qfa[m], sA, 0, 0, 0);
        PROC(sB, kt == qtb, mB, lB, aB0, aB1, vf0, vf1);
        PROC(sA, kt == qta, mA, lA, aA0, aA1, vf0, vf1);
      } else {
        PROC(sB, kt == qtb, mB, lB, aB0, aB1, vf0, vf1);
      }
    }

    if (pre) {
      *(uint4*)&Ks[cur^1][ks_row*68 + ks_c*8] = kn2;
      *(uint4*)&Vs[cur^1][vs_row*44 + vs_c*8] = vn2;
    }
    __syncthreads();
  }

  // epilogue: O[dv][q] regs -> LDS transpose -> coalesced global store
  const int b = bh >> 4, h = bh & 15;
  auto EPI = [&](int qt, float lS, const f32x16& o0, const f32x16& o1) {
    float inv = 1.0f / lS;
    ushort* o = &OT[w][0];
    #pragma unroll
    for (int r2=0;r2<8;r2++) {
      int r = 2*r2;
      int dv = (r&3) + ((r>>2)<<3) + 4*hi;
      *(unsigned*)&o[col*72 + dv]      = cvtpk(o0[r]*inv, o0[r+1]*inv);
      *(unsigned*)&o[col*72 + 32 + dv] = cvtpk(o1[r]*inv, o1[r+1]*inv);
    }
    #pragma unroll
    for (int it=0; it<4; ++it) {
      int q = it*8 + (l>>3), c8 = (l&7)*8;
      uint4 v = *(const uint4*)&o[q*72 + c8];
      int qg = qt*32 + q;
      *(uint4*)&Ob[(size_t)(b*1024+qg)*1024 + h*64 + c8] = v;
    }
  };
  EPI(qta, lA, aA0, aA1);
  EPI(qtb, lB, aB0, aB1);
}

extern "C" void kernel_launch(void* const* d_in, const int* in_sizes, int n_in,
                              void* d_out, int out_size, void* d_ws, size_t ws_size,
                              hipStream_t stream) {
  const float* query = (const float*)d_in[0];
  const float* Wq = (const float*)d_in[4];
  const float* bq = (const float*)d_in[5];
  const float* Wk = (const float*)d_in[6];
  const float* bk = (const float*)d_in[7];
  const float* Wv = (const float*)d_in[8];
  const float* bv = (const float*)d_in[9];
  const float* Wo = (const float*)d_in[10];
  const float* bo = (const float*)d_in[11];

  char* wsb = (char*)d_ws;
  ushort* Xb   = (ushort*)(wsb);                  // 16 MB
  ushort* Wqkv = (ushort*)(wsb + 16777216);       // 6 MB
  float*  Bqkv = (float*) (wsb + 23068672);       // 12 KB
  ushort* Wob  = (ushort*)(wsb + 23080960);       // 2 MB
  ushort* Qb   = (ushort*)(wsb + 25178112);       // 16 MB
  ushort* Kb   = (ushort*)(wsb + 41955328);       // 16 MB
  ushort* Vtb  = (ushort*)(wsb + 58732544);       // 16 MB  [bh][d][s]
  ushort* Ob   = (ushort*)(wsb + 75509760);       // 16 MB

  hipLaunchKernelGGL(pack_all_kern, dim3(5120), dim3(256), 0, stream,
                     query, Xb, Wq, Wk, Wv, bq, bk, bv, Wo, Wqkv, Bqkv, Wob);
  hipLaunchKernelGGL(gemmw8_kern, dim3(384), dim3(512), 0, stream,
                     Xb, Wqkv, Bqkv, Qb, Kb, Vtb);
  hipLaunchKernelGGL(attn_kern, dim3(512), dim3(256), 0, stream, Qb, Kb, Vtb, Ob);
  hipLaunchKernelGGL(gemm128_kern<1>, dim3(512), dim3(256), 0, stream,
                     Ob, Wob, bo, (ushort*)nullptr, (ushort*)nullptr, (ushort*)nullptr,
                     (float*)d_out);
}

// Round 17
// 145.560 us; speedup vs baseline: 1.0592x; 1.0592x over previous
//
#include <hip/hip_runtime.h>
#include <hip/hip_bf16.h>

#define B_ 8
#define S_ 1024
#define U_ 1024
#define H_ 16
#define DK_ 64

typedef __attribute__((ext_vector_type(8))) short short8;
typedef __attribute__((ext_vector_type(4))) float f32x4;
typedef __attribute__((ext_vector_type(16))) float f32x16;

__device__ inline ushort f2b(float x) {
  union { float f; unsigned u; } v; v.f = x;
  unsigned r = (v.u + 0x7FFFu + ((v.u >> 16) & 1u)) >> 16;
  return (ushort)r;
}
__device__ inline unsigned cvtpk(float lo, float hi) {
  unsigned r;
  asm("v_cvt_pk_bf16_f32 %0, %1, %2" : "=v"(r) : "v"(lo), "v"(hi));
  return r;
}

__device__ inline void gld16(const ushort* g, ushort* l) {
  __builtin_amdgcn_global_load_lds((__attribute__((address_space(1))) void*)(g),
                                   (__attribute__((address_space(3))) void*)(l),
                                   16, 0, 0);
}

// ------------- fused pack: query fp32->bf16 + weight transpose ---------------
__global__ __launch_bounds__(256) void pack_all_kern(
    const float* __restrict__ X, ushort* __restrict__ Xb,
    const float* __restrict__ Wq, const float* __restrict__ Wk, const float* __restrict__ Wv,
    const float* __restrict__ bq, const float* __restrict__ bk, const float* __restrict__ bv,
    const float* __restrict__ Wo,
    ushort* __restrict__ Wqkv, float* __restrict__ Bqkv, ushort* __restrict__ Wob)
{
  __shared__ ushort tile[64*65];
  const int t = threadIdx.x;
  if (blockIdx.x < 4096) {
    int idx = blockIdx.x * 256 + t;
    const float4* src = (const float4*)X + (size_t)idx * 2;
    float4 a = src[0], b = src[1];
    ushort r[8];
    r[0]=f2b(a.x); r[1]=f2b(a.y); r[2]=f2b(a.z); r[3]=f2b(a.w);
    r[4]=f2b(b.x); r[5]=f2b(b.y); r[6]=f2b(b.z); r[7]=f2b(b.w);
    *(uint4*)(Xb + (size_t)idx*8) = *(uint4*)r;
    return;
  }
  const int bid = blockIdx.x - 4096;
  if (bid < 768) {
    int p = bid >> 8, rem = bid & 255;
    int h = rem >> 4, kc = rem & 15, k0 = kc*64;
    const float* Wsrc = (p==0) ? Wq : ((p==1) ? Wk : Wv);
    #pragma unroll
    for (int i = 0; i < 16; ++i) {
      int e = t + i*256;
      int r = e >> 6, d = e & 63;
      tile[d*65 + r] = f2b(Wsrc[h*65536 + (k0+r)*64 + d]);
    }
    __syncthreads();
    #pragma unroll
    for (int i = 0; i < 16; ++i) {
      int e = t + i*256;
      int d = e >> 6, r = e & 63;
      Wqkv[(size_t)(p*1024 + h*64 + d)*1024 + k0 + r] = tile[d*65 + r];
    }
    if (kc == 0 && t < 64) {
      const float* bsrc = (p==0) ? bq : ((p==1) ? bk : bv);
      Bqkv[p*1024 + h*64 + t] = bsrc[h*64 + t];
    }
  } else {
    int b2 = bid - 768;
    int nc = b2 >> 4, kc = b2 & 15;
    int n0 = nc*64, k0 = kc*64;
    #pragma unroll
    for (int i = 0; i < 16; ++i) {
      int e = t + i*256;
      int r = e >> 6, d = e & 63;
      tile[d*65 + r] = f2b(Wo[(size_t)(k0+r)*1024 + n0 + d]);
    }
    __syncthreads();
    #pragma unroll
    for (int i = 0; i < 16; ++i) {
      int e = t + i*256;
      int d = e >> 6, r = e & 63;
      Wob[(size_t)(n0+d)*1024 + k0 + r] = tile[d*65 + r];
    }
  }
}

// ---- QKV GEMM: 128x128x32, TRIPLE buffer, 3 blk/CU (r12 best, standalone) --
// Per K-step: vmcnt(4) [counted] -> bar -> 8 ds_read -> bar -> stage kt+2 into
// slot (kt+2)%3 -> 16 MFMA. Never vmcnt(0). XOR-chunk swizzle both-sides.
// Epilogue: Q (x0.125*log2e) [bh][s][d], K [bh][s][d], V transposed [bh][d][s].
__global__ __launch_bounds__(256, 3) void gemm0_kern(
    const ushort* __restrict__ A,
    const ushort* __restrict__ Bw,
    const float* __restrict__ bias,
    ushort* __restrict__ Qb, ushort* __restrict__ Kb, ushort* __restrict__ Vtb)
{
  __shared__ __align__(16) ushort As[3][4096];
  __shared__ __align__(16) ushort Bs[3][4096];

  const int t = threadIdx.x;
  const int l = t & 63, w = t >> 6;
  const int wr = w >> 1, wc = w & 1;
  const int li = l & 15, c4 = l >> 4;

  // 1536 blocks = 64m x 24n; XCD chunk 192 = 8m x 24n (bijective)
  const int swz = (blockIdx.x & 7) * 192 + (blockIdx.x >> 3);
  const int ms = swz / 192, rem = swz % 192;
  const int m0 = (ms*8 + (rem & 7)) * 128;
  const int n0 = (rem >> 3) * 128;

  f32x4 acc[4][4];
  #pragma unroll
  for (int i=0;i<4;i++)
    #pragma unroll
    for (int j=0;j<4;j++) acc[i][j] = (f32x4)0.0f;

  auto SA = [&](int buf, int kk) {
    #pragma unroll
    for (int p2=0;p2<2;++p2) {
      int n = p2*256 + t;
      int row = n >> 2, jj = (n & 3) ^ ((row >> 1) & 3);
      gld16(&A[(size_t)(m0 + row)*1024 + kk + jj*8], &As[buf][n*8]);
    }
  };
  auto SB = [&](int buf, int kk) {
    #pragma unroll
    for (int p2=0;p2<2;++p2) {
      int n = p2*256 + t;
      int row = n >> 2, jj = (n & 3) ^ ((row >> 1) & 3);
      gld16(&Bw[(size_t)(n0 + row)*1024 + kk + jj*8], &Bs[buf][n*8]);
    }
  };

  SA(0, 0);  SB(0, 0);
  SA(1, 32); SB(1, 32);

  for (int kt = 0; kt < 32; ++kt) {
    const int cur = kt % 3;
    asm volatile("s_waitcnt vmcnt(4)" ::: "memory");
    __builtin_amdgcn_s_barrier();
    __builtin_amdgcn_sched_barrier(0);

    short8 af[4], bf[4];
    #pragma unroll
    for (int i=0;i<4;i++) {
      int rA = wr*64 + i*16 + li;
      int rB = wc*64 + i*16 + li;
      af[i] = *(const short8*)&As[cur][rA*32 + ((c4 ^ ((rA>>1)&3))*8)];
      bf[i] = *(const short8*)&Bs[cur][rB*32 + ((c4 ^ ((rB>>1)&3))*8)];
    }
    __builtin_amdgcn_s_barrier();
    __builtin_amdgcn_sched_barrier(0);
    const int nb = (kt + 2) % 3;
    const int kk2 = ((kt + 2) & 31) * 32;
    SA(nb, kk2); SB(nb, kk2);

    __builtin_amdgcn_s_setprio(1);
    #pragma unroll
    for (int i=0;i<4;i++)
      #pragma unroll
      for (int j=0;j<4;j++)
        acc[i][j] = __builtin_amdgcn_mfma_f32_16x16x32_bf16(af[i], bf[j], acc[i][j], 0,0,0);
    __builtin_amdgcn_s_setprio(0);
  }

  #pragma unroll
  for (int i=0;i<4;i++) {
    int rbase = m0 + wr*64 + i*16 + c4*4;
    #pragma unroll
    for (int j=0;j<4;j++) {
      int col = n0 + wc*64 + j*16 + li;
      float bv = bias[col];
      int p = col >> 10, h = (col >> 6) & 15, d = col & 63;
      int b = rbase >> 10, s = rbase & 1023;
      if (p == 2) {            // V -> transposed [bh][d][s], 8B packed store
        unsigned pk4[2];
        pk4[0] = cvtpk(acc[i][j][0] + bv, acc[i][j][1] + bv);
        pk4[1] = cvtpk(acc[i][j][2] + bv, acc[i][j][3] + bv);
        *(uint2*)&Vtb[((size_t)((b*16+h)*64 + d))*1024 + s] = *(uint2*)pk4;
      } else {
        ushort* dst = (p==0) ? Qb : Kb;
        float sc = (p==0) ? 0.18033688011112042f : 1.0f;   // 0.125*log2(e)
        #pragma unroll
        for (int r=0;r<4;r++)
          dst[(((size_t)(b*16 + h))*1024 + s + r)*64 + d] = f2b((acc[i][j][r] + bv) * sc);
      }
    }
  }
}

// ---- out-proj GEMM: 128x128x32 triple buffer (frozen; sole instantiation) --
template<int MODE>
__global__ __launch_bounds__(256, 3) void gemm128_kern(
    const ushort* __restrict__ A,
    const ushort* __restrict__ Bw,
    const float* __restrict__ bias,
    ushort* __restrict__ Qb, ushort* __restrict__ Kb, ushort* __restrict__ Vtb,
    float* __restrict__ outF)
{
  __shared__ __align__(16) ushort As[3][4096];
  __shared__ __align__(16) ushort Bs[3][4096];

  const int t = threadIdx.x;
  const int l = t & 63, w = t >> 6;
  const int wr = w >> 1, wc = w & 1;
  const int li = l & 15, c4 = l >> 4;

  int m0, n0;
  {
    int swz = (blockIdx.x & 7) * 64 + (blockIdx.x >> 3);
    int ms = swz / 64, rem = swz % 64;
    m0 = (ms*8 + (rem & 7)) * 128;  n0 = (rem >> 3) * 128;
  }

  f32x4 acc[4][4];
  #pragma unroll
  for (int i=0;i<4;i++)
    #pragma unroll
    for (int j=0;j<4;j++) acc[i][j] = (f32x4)0.0f;

  auto SA = [&](int buf, int kk) {
    #pragma unroll
    for (int p2=0;p2<2;++p2) {
      int n = p2*256 + t;
      int row = n >> 2, jj = (n & 3) ^ ((row >> 1) & 3);
      gld16(&A[(size_t)(m0 + row)*1024 + kk + jj*8], &As[buf][n*8]);
    }
  };
  auto SB = [&](int buf, int kk) {
    #pragma unroll
    for (int p2=0;p2<2;++p2) {
      int n = p2*256 + t;
      int row = n >> 2, jj = (n & 3) ^ ((row >> 1) & 3);
      gld16(&Bw[(size_t)(n0 + row)*1024 + kk + jj*8], &Bs[buf][n*8]);
    }
  };

  SA(0, 0);  SB(0, 0);
  SA(1, 32); SB(1, 32);

  for (int kt = 0; kt < 32; ++kt) {
    const int cur = kt % 3;
    asm volatile("s_waitcnt vmcnt(4)" ::: "memory");
    __builtin_amdgcn_s_barrier();
    __builtin_amdgcn_sched_barrier(0);

    short8 af[4], bf[4];
    #pragma unroll
    for (int i=0;i<4;i++) {
      int rA = wr*64 + i*16 + li;
      int rB = wc*64 + i*16 + li;
      af[i] = *(const short8*)&As[cur][rA*32 + ((c4 ^ ((rA>>1)&3))*8)];
      bf[i] = *(const short8*)&Bs[cur][rB*32 + ((c4 ^ ((rB>>1)&3))*8)];
    }
    __builtin_amdgcn_s_barrier();
    __builtin_amdgcn_sched_barrier(0);
    const int nb = (kt + 2) % 3;
    const int kk2 = ((kt + 2) & 31) * 32;
    SA(nb, kk2); SB(nb, kk2);

    __builtin_amdgcn_s_setprio(1);
    #pragma unroll
    for (int i=0;i<4;i++)
      #pragma unroll
      for (int j=0;j<4;j++)
        acc[i][j] = __builtin_amdgcn_mfma_f32_16x16x32_bf16(af[i], bf[j], acc[i][j], 0,0,0);
    __builtin_amdgcn_s_setprio(0);
  }

  #pragma unroll
  for (int i=0;i<4;i++) {
    int rbase = m0 + wr*64 + i*16 + c4*4;
    #pragma unroll
    for (int j=0;j<4;j++) {
      int col = n0 + wc*64 + j*16 + li;
      float bv = bias[col];
      #pragma unroll
      for (int r=0;r<4;r++)
        outF[(size_t)(rbase+r)*1024 + col] = acc[i][j][r] + bv;
    }
  }
}

// ------- causal flash attention: block-staged K/V + cvt_pk/max3 (frozen) ----
__global__ __launch_bounds__(256, 2) void attn_kern(
    const ushort* __restrict__ Qb, const ushort* __restrict__ Kb,
    const ushort* __restrict__ Vt, ushort* __restrict__ Ob)
{
  __shared__ __align__(16) ushort Ks[2][32*68];   // [s][d] stride 68
  __shared__ __align__(16) ushort Vs[2][64*44];   // [dv][s32] stride 44
  __shared__ __align__(16) ushort Pb[4][32*40];   // per-wave P [q][kv]
  __shared__ __align__(16) ushort OT[4][32*72];   // per-wave epilogue transpose
  const int t = threadIdx.x, l = t & 63, w = t >> 6;
  const int bid = blockIdx.x;
  const int x = bid & 7, i0 = bid >> 3;
  const int bh = x*16 + (i0 >> 2);                // bh clustered per XCD
  const int g  = i0 & 3;
  const int p  = g*4 + w;
  const int qta = p, qtb = 31 - p;
  const int NT = 32 - g*4;                        // block-uniform tile count

  const int col = l & 31, hi = l >> 5;
  const ushort* Qp = Qb + (size_t)bh*65536;
  const ushort* Kp = Kb + (size_t)bh*65536;
  const ushort* Vp = Vt + (size_t)bh*65536;

  const int ks_row = t >> 3, ks_c = t & 7;
  const int vs_row = t >> 2, vs_c = t & 3;

  short8 qfa[4], qfb[4];
  #pragma unroll
  for (int m=0;m<4;m++) {
    qfa[m] = *(const short8*)&Qp[(size_t)(qta*32+col)*64 + m*16 + hi*8];
    qfb[m] = *(const short8*)&Qp[(size_t)(qtb*32+col)*64 + m*16 + hi*8];
  }

  f32x16 aA0 = (f32x16)0.0f, aA1 = (f32x16)0.0f;
  f32x16 aB0 = (f32x16)0.0f, aB1 = (f32x16)0.0f;
  float mA = -1e30f, lA = 0.0f, mB = -1e30f, lB = 0.0f;
  ushort* Pw = &Pb[w][0];

  auto PROC = [&](f32x16& s, bool diag, float& mR, float& lS,
                  f32x16& o0, f32x16& o1, const short8* vf0, const short8* vf1) {
    if (diag) {
      #pragma unroll
      for (int r=0;r<16;r++) {
        int kvl = (r&3) + ((r>>2)<<3) + 4*hi;
        s[r] = (kvl > col) ? -1e9f : s[r];
      }
    }
    float t0 = fmaxf(fmaxf(s[0], s[1]), s[2]);
    float t1 = fmaxf(fmaxf(s[3], s[4]), s[5]);
    float t2 = fmaxf(fmaxf(s[6], s[7]), s[8]);
    float t3 = fmaxf(fmaxf(s[9], s[10]), s[11]);
    float t4 = fmaxf(fmaxf(s[12], s[13]), s[14]);
    float mx = fmaxf(fmaxf(fmaxf(t0, t1), t2), fmaxf(fmaxf(t3, t4), s[15]));
    mx = fmaxf(mx, __shfl_xor(mx, 32));
    if (__any(mx - mR > 8.0f)) {          // T13 defer-max (log2 units)
      float mN = fmaxf(mR, mx);
      float corr = __builtin_amdgcn_exp2f(mR - mN);
      mR = mN; lS *= corr;
      #pragma unroll
      for (int r=0;r<16;r++) { o0[r] *= corr; o1[r] *= corr; }
    }
    float pr[16];
    #pragma unroll
    for (int r=0;r<16;r++) pr[r] = __builtin_amdgcn_exp2f(s[r] - mR);
    float s8[8];
    #pragma unroll
    for (int r2=0;r2<8;r2++) s8[r2] = pr[2*r2] + pr[2*r2+1];
    #pragma unroll
    for (int r2=0;r2<4;r2++) s8[r2] += s8[r2+4];
    float rs = (s8[0]+s8[1]) + (s8[2]+s8[3]);
    rs += __shfl_xor(rs, 32);
    lS += rs;
    #pragma unroll
    for (int r2=0;r2<8;r2++) {
      int r = 2*r2;
      int kv = (r&3) + ((r>>2)<<3) + 4*hi;
      *(unsigned*)&Pw[col*40 + kv] = cvtpk(pr[r], pr[r+1]);
    }
    short8 pb0 = *(const short8*)&Pw[col*40 + hi*8];
    short8 pb1 = *(const short8*)&Pw[col*40 + 16 + hi*8];
    o0 = __builtin_amdgcn_mfma_f32_32x32x16_bf16(vf0[0], pb0, o0, 0,0,0);
    o0 = __builtin_amdgcn_mfma_f32_32x32x16_bf16(vf0[1], pb1, o0, 0,0,0);
    o1 = __builtin_amdgcn_mfma_f32_32x32x16_bf16(vf1[0], pb0, o1, 0,0,0);
    o1 = __builtin_amdgcn_mfma_f32_32x32x16_bf16(vf1[1], pb1, o1, 0,0,0);
  };

  { // stage tile 0 into buf 0
    uint4 k0v = *(const uint4*)&Kp[(size_t)ks_row*64 + ks_c*8];
    uint4 v0v = *(const uint4*)&Vp[(size_t)vs_row*1024 + vs_c*8];
    *(uint4*)&Ks[0][ks_row*68 + ks_c*8] = k0v;
    *(uint4*)&Vs[0][vs_row*44 + vs_c*8] = v0v;
  }
  __syncthreads();

  for (int kt = 0; kt < NT; ++kt) {
    const int cur = kt & 1;
    const bool pre = (kt + 1 < NT);
    uint4 kn2, vn2;
    if (pre) {   // T14: global prefetch of tile kt+1 (overlaps PROC below)
      kn2 = *(const uint4*)&Kp[(size_t)((kt+1)*32+ks_row)*64 + ks_c*8];
      vn2 = *(const uint4*)&Vp[(size_t)vs_row*1024 + (kt+1)*32 + vs_c*8];
    }

    short8 kf[4], vf0[2], vf1[2];
    #pragma unroll
    for (int m=0;m<4;m++)
      kf[m] = *(const short8*)&Ks[cur][col*68 + m*16 + hi*8];
    #pragma unroll
    for (int m=0;m<2;m++) {
      vf0[m] = *(const short8*)&Vs[cur][col*44 + m*16 + hi*8];
      vf1[m] = *(const short8*)&Vs[cur][(col+32)*44 + m*16 + hi*8];
    }

    const bool doB = (kt <= qtb), doA = (kt <= qta);
    if (doB) {
      f32x16 sB = (f32x16)0.0f;
      #pragma unroll
      for (int m=0;m<4;m++)
        sB = __builtin_amdgcn_mfma_f32_32x32x16_bf16(kf[m], qfb[m], sB, 0, 0, 0);
      if (doA) {
        f32x16 sA = (f32x16)0.0f;
        #pragma unroll
        for (int m=0;m<4;m++)
          sA = __builtin_amdgcn_mfma_f32_32x32x16_bf16(kf[m], qfa[m], sA, 0, 0, 0);
        PROC(sB, kt == qtb, mB, lB, aB0, aB1, vf0, vf1);
        PROC(sA, kt == qta, mA, lA, aA0, aA1, vf0, vf1);
      } else {
        PROC(sB, kt == qtb, mB, lB, aB0, aB1, vf0, vf1);
      }
    }

    if (pre) {
      *(uint4*)&Ks[cur^1][ks_row*68 + ks_c*8] = kn2;
      *(uint4*)&Vs[cur^1][vs_row*44 + vs_c*8] = vn2;
    }
    __syncthreads();
  }

  // epilogue: O[dv][q] regs -> LDS transpose -> coalesced global store
  const int b = bh >> 4, h = bh & 15;
  auto EPI = [&](int qt, float lS, const f32x16& o0, const f32x16& o1) {
    float inv = 1.0f / lS;
    ushort* o = &OT[w][0];
    #pragma unroll
    for (int r2=0;r2<8;r2++) {
      int r = 2*r2;
      int dv = (r&3) + ((r>>2)<<3) + 4*hi;
      *(unsigned*)&o[col*72 + dv]      = cvtpk(o0[r]*inv, o0[r+1]*inv);
      *(unsigned*)&o[col*72 + 32 + dv] = cvtpk(o1[r]*inv, o1[r+1]*inv);
    }
    #pragma unroll
    for (int it=0; it<4; ++it) {
      int q = it*8 + (l>>3), c8 = (l&7)*8;
      uint4 v = *(const uint4*)&o[q*72 + c8];
      int qg = qt*32 + q;
      *(uint4*)&Ob[(size_t)(b*1024+qg)*1024 + h*64 + c8] = v;
    }
  };
  EPI(qta, lA, aA0, aA1);
  EPI(qtb, lB, aB0, aB1);
}

extern "C" void kernel_launch(void* const* d_in, const int* in_sizes, int n_in,
                              void* d_out, int out_size, void* d_ws, size_t ws_size,
                              hipStream_t stream) {
  const float* query = (const float*)d_in[0];
  const float* Wq = (const float*)d_in[4];
  const float* bq = (const float*)d_in[5];
  const float* Wk = (const float*)d_in[6];
  const float* bk = (const float*)d_in[7];
  const float* Wv = (const float*)d_in[8];
  const float* bv = (const float*)d_in[9];
  const float* Wo = (const float*)d_in[10];
  const float* bo = (const float*)d_in[11];

  char* wsb = (char*)d_ws;
  ushort* Xb   = (ushort*)(wsb);                  // 16 MB
  ushort* Wqkv = (ushort*)(wsb + 16777216);       // 6 MB
  float*  Bqkv = (float*) (wsb + 23068672);       // 12 KB
  ushort* Wob  = (ushort*)(wsb + 23080960);       // 2 MB
  ushort* Qb   = (ushort*)(wsb + 25178112);       // 16 MB
  ushort* Kb   = (ushort*)(wsb + 41955328);       // 16 MB
  ushort* Vtb  = (ushort*)(wsb + 58732544);       // 16 MB  [bh][d][s]
  ushort* Ob   = (ushort*)(wsb + 75509760);       // 16 MB

  hipLaunchKernelGGL(pack_all_kern, dim3(5120), dim3(256), 0, stream,
                     query, Xb, Wq, Wk, Wv, bq, bk, bv, Wo, Wqkv, Bqkv, Wob);
  hipLaunchKernelGGL(gemm0_kern, dim3(1536), dim3(256), 0, stream,
                     Xb, Wqkv, Bqkv, Qb, Kb, Vtb);
  hipLaunchKernelGGL(attn_kern, dim3(512), dim3(256), 0, stream, Qb, Kb, Vtb, Ob);
  hipLaunchKernelGGL(gemm128_kern<1>, dim3(512), dim3(256), 0, stream,
                     Ob, Wob, bo, (ushort*)nullptr, (ushort*)nullptr, (ushort*)nullptr,
                     (float*)d_out);
}

// Round 18
// 143.079 us; speedup vs baseline: 1.0775x; 1.0173x over previous
//
#include <hip/hip_runtime.h>
#include <hip/hip_bf16.h>

#define B_ 8
#define S_ 1024
#define U_ 1024
#define H_ 16
#define DK_ 64

typedef __attribute__((ext_vector_type(8))) short short8;
typedef __attribute__((ext_vector_type(4))) float f32x4;
typedef __attribute__((ext_vector_type(16))) float f32x16;

__device__ inline ushort f2b(float x) {
  union { float f; unsigned u; } v; v.f = x;
  unsigned r = (v.u + 0x7FFFu + ((v.u >> 16) & 1u)) >> 16;
  return (ushort)r;
}
// packed bf16 convert (RNE, same as f2b) - 1 instr instead of ~8
__device__ inline unsigned cvtpk(float lo, float hi) {
  unsigned r;
  asm("v_cvt_pk_bf16_f32 %0, %1, %2" : "=v"(r) : "v"(lo), "v"(hi));
  return r;
}

__device__ inline void gld16(const ushort* g, ushort* l) {
  __builtin_amdgcn_global_load_lds((__attribute__((address_space(1))) void*)(g),
                                   (__attribute__((address_space(3))) void*)(l),
                                   16, 0, 0);
}

// ------------- fused pack: query fp32->bf16 + weight transpose ---------------
__global__ __launch_bounds__(256) void pack_all_kern(
    const float* __restrict__ X, ushort* __restrict__ Xb,
    const float* __restrict__ Wq, const float* __restrict__ Wk, const float* __restrict__ Wv,
    const float* __restrict__ bq, const float* __restrict__ bk, const float* __restrict__ bv,
    const float* __restrict__ Wo,
    ushort* __restrict__ Wqkv, float* __restrict__ Bqkv, ushort* __restrict__ Wob)
{
  __shared__ ushort tile[64*65];
  const int t = threadIdx.x;
  if (blockIdx.x < 4096) {
    int idx = blockIdx.x * 256 + t;
    const float4* src = (const float4*)X + (size_t)idx * 2;
    float4 a = src[0], b = src[1];
    ushort r[8];
    r[0]=f2b(a.x); r[1]=f2b(a.y); r[2]=f2b(a.z); r[3]=f2b(a.w);
    r[4]=f2b(b.x); r[5]=f2b(b.y); r[6]=f2b(b.z); r[7]=f2b(b.w);
    *(uint4*)(Xb + (size_t)idx*8) = *(uint4*)r;
    return;
  }
  const int bid = blockIdx.x - 4096;
  if (bid < 768) {
    int p = bid >> 8, rem = bid & 255;
    int h = rem >> 4, kc = rem & 15, k0 = kc*64;
    const float* Wsrc = (p==0) ? Wq : ((p==1) ? Wk : Wv);
    #pragma unroll
    for (int i = 0; i < 16; ++i) {
      int e = t + i*256;
      int r = e >> 6, d = e & 63;
      tile[d*65 + r] = f2b(Wsrc[h*65536 + (k0+r)*64 + d]);
    }
    __syncthreads();
    #pragma unroll
    for (int i = 0; i < 16; ++i) {
      int e = t + i*256;
      int d = e >> 6, r = e & 63;
      Wqkv[(size_t)(p*1024 + h*64 + d)*1024 + k0 + r] = tile[d*65 + r];
    }
    if (kc == 0 && t < 64) {
      const float* bsrc = (p==0) ? bq : ((p==1) ? bk : bv);
      Bqkv[p*1024 + h*64 + t] = bsrc[h*64 + t];
    }
  } else {
    int b2 = bid - 768;
    int nc = b2 >> 4, kc = b2 & 15;
    int n0 = nc*64, k0 = kc*64;
    #pragma unroll
    for (int i = 0; i < 16; ++i) {
      int e = t + i*256;
      int r = e >> 6, d = e & 63;
      tile[d*65 + r] = f2b(Wo[(size_t)(k0+r)*1024 + n0 + d]);
    }
    __syncthreads();
    #pragma unroll
    for (int i = 0; i < 16; ++i) {
      int e = t + i*256;
      int d = e >> 6, r = e & 63;
      Wob[(size_t)(n0+d)*1024 + k0 + r] = tile[d*65 + r];
    }
  }
}

// ---- QKV GEMM: 256x128x32, per-wave C=128x64, triple buffer (r15 best) -----
__global__ __launch_bounds__(256, 2) void gemmw_kern(
    const ushort* __restrict__ A,
    const ushort* __restrict__ Bw,
    const float* __restrict__ bias,
    ushort* __restrict__ Qb, ushort* __restrict__ Kb, ushort* __restrict__ Vtb)
{
  __shared__ __align__(16) ushort As[3][8192];   // [buf][(row 0..255)*32+col]
  __shared__ __align__(16) ushort Bs[3][4096];   // [buf][(row 0..127)*32+col]

  const int t = threadIdx.x;
  const int l = t & 63, w = t >> 6;
  const int wr = w >> 1, wc = w & 1;
  const int li = l & 15, c4 = l >> 4;

  const int swz = (blockIdx.x & 7) * 96 + (blockIdx.x >> 3);
  const int ms = swz / 96, rem = swz % 96;
  const int m0 = (ms*4 + (rem & 3)) * 256;
  const int n0 = (rem >> 2) * 128;

  f32x4 acc[8][4];
  #pragma unroll
  for (int i=0;i<8;i++)
    #pragma unroll
    for (int j=0;j<4;j++) acc[i][j] = (f32x4)0.0f;

  auto SA = [&](int buf, int kk) {
    #pragma unroll
    for (int p2=0;p2<4;++p2) {
      int n = p2*256 + t;
      int row = n >> 2, jj = (n & 3) ^ ((row >> 1) & 3);
      gld16(&A[(size_t)(m0 + row)*1024 + kk + jj*8], &As[buf][n*8]);
    }
  };
  auto SB = [&](int buf, int kk) {
    #pragma unroll
    for (int p2=0;p2<2;++p2) {
      int n = p2*256 + t;
      int row = n >> 2, jj = (n & 3) ^ ((row >> 1) & 3);
      gld16(&Bw[(size_t)(n0 + row)*1024 + kk + jj*8], &Bs[buf][n*8]);
    }
  };

  SA(0, 0);  SB(0, 0);
  SA(1, 32); SB(1, 32);

  for (int kt = 0; kt < 32; ++kt) {
    const int cur = kt % 3;
    asm volatile("s_waitcnt vmcnt(6)" ::: "memory");
    __builtin_amdgcn_s_barrier();
    __builtin_amdgcn_sched_barrier(0);

    short8 af[8], bf[4];
    #pragma unroll
    for (int i=0;i<8;i++) {
      int rA = wr*128 + i*16 + li;
      af[i] = *(const short8*)&As[cur][rA*32 + ((c4 ^ ((rA>>1)&3))*8)];
    }
    #pragma unroll
    for (int j=0;j<4;j++) {
      int rB = wc*64 + j*16 + li;
      bf[j] = *(const short8*)&Bs[cur][rB*32 + ((c4 ^ ((rB>>1)&3))*8)];
    }
    __builtin_amdgcn_s_barrier();
    __builtin_amdgcn_sched_barrier(0);
    const int nb = (kt + 2) % 3;
    const int kk2 = ((kt + 2) & 31) * 32;
    SA(nb, kk2); SB(nb, kk2);

    __builtin_amdgcn_s_setprio(1);
    #pragma unroll
    for (int i=0;i<8;i++)
      #pragma unroll
      for (int j=0;j<4;j++)
        acc[i][j] = __builtin_amdgcn_mfma_f32_16x16x32_bf16(af[i], bf[j], acc[i][j], 0,0,0);
    __builtin_amdgcn_s_setprio(0);
  }

  #pragma unroll
  for (int i=0;i<8;i++) {
    int rbase = m0 + wr*128 + i*16 + c4*4;
    #pragma unroll
    for (int j=0;j<4;j++) {
      int col = n0 + wc*64 + j*16 + li;
      float bv = bias[col];
      int p = col >> 10, h = (col >> 6) & 15, d = col & 63;
      int b = rbase >> 10, s = rbase & 1023;
      if (p == 2) {            // V -> transposed [bh][d][s], 8B packed store
        unsigned pk4[2];
        pk4[0] = cvtpk(acc[i][j][0] + bv, acc[i][j][1] + bv);
        pk4[1] = cvtpk(acc[i][j][2] + bv, acc[i][j][3] + bv);
        *(uint2*)&Vtb[((size_t)((b*16+h)*64 + d))*1024 + s] = *(uint2*)pk4;
      } else {
        ushort* dst = (p==0) ? Qb : Kb;
        float sc = (p==0) ? 0.18033688011112042f : 1.0f;   // 0.125*log2(e)
        #pragma unroll
        for (int r=0;r<4;r++)
          dst[(((size_t)(b*16 + h))*1024 + s + r)*64 + d] = f2b((acc[i][j][r] + bv) * sc);
      }
    }
  }
}

// ---- out-proj GEMM: 128x128x32 triple buffer (frozen) ----------------------
template<int MODE>
__global__ __launch_bounds__(256, 3) void gemm128_kern(
    const ushort* __restrict__ A,
    const ushort* __restrict__ Bw,
    const float* __restrict__ bias,
    ushort* __restrict__ Qb, ushort* __restrict__ Kb, ushort* __restrict__ Vtb,
    float* __restrict__ outF)
{
  __shared__ __align__(16) ushort As[3][4096];
  __shared__ __align__(16) ushort Bs[3][4096];

  const int t = threadIdx.x;
  const int l = t & 63, w = t >> 6;
  const int wr = w >> 1, wc = w & 1;
  const int li = l & 15, c4 = l >> 4;

  int m0, n0;
  {
    int swz = (blockIdx.x & 7) * 64 + (blockIdx.x >> 3);
    int ms = swz / 64, rem = swz % 64;
    m0 = (ms*8 + (rem & 7)) * 128;  n0 = (rem >> 3) * 128;
  }

  f32x4 acc[4][4];
  #pragma unroll
  for (int i=0;i<4;i++)
    #pragma unroll
    for (int j=0;j<4;j++) acc[i][j] = (f32x4)0.0f;

  auto SA = [&](int buf, int kk) {
    #pragma unroll
    for (int p2=0;p2<2;++p2) {
      int n = p2*256 + t;
      int row = n >> 2, jj = (n & 3) ^ ((row >> 1) & 3);
      gld16(&A[(size_t)(m0 + row)*1024 + kk + jj*8], &As[buf][n*8]);
    }
  };
  auto SB = [&](int buf, int kk) {
    #pragma unroll
    for (int p2=0;p2<2;++p2) {
      int n = p2*256 + t;
      int row = n >> 2, jj = (n & 3) ^ ((row >> 1) & 3);
      gld16(&Bw[(size_t)(n0 + row)*1024 + kk + jj*8], &Bs[buf][n*8]);
    }
  };

  SA(0, 0);  SB(0, 0);
  SA(1, 32); SB(1, 32);

  for (int kt = 0; kt < 32; ++kt) {
    const int cur = kt % 3;
    asm volatile("s_waitcnt vmcnt(4)" ::: "memory");
    __builtin_amdgcn_s_barrier();
    __builtin_amdgcn_sched_barrier(0);

    short8 af[4], bf[4];
    #pragma unroll
    for (int i=0;i<4;i++) {
      int rA = wr*64 + i*16 + li;
      int rB = wc*64 + i*16 + li;
      af[i] = *(const short8*)&As[cur][rA*32 + ((c4 ^ ((rA>>1)&3))*8)];
      bf[i] = *(const short8*)&Bs[cur][rB*32 + ((c4 ^ ((rB>>1)&3))*8)];
    }
    __builtin_amdgcn_s_barrier();
    __builtin_amdgcn_sched_barrier(0);
    const int nb = (kt + 2) % 3;
    const int kk2 = ((kt + 2) & 31) * 32;
    SA(nb, kk2); SB(nb, kk2);

    __builtin_amdgcn_s_setprio(1);
    #pragma unroll
    for (int i=0;i<4;i++)
      #pragma unroll
      for (int j=0;j<4;j++)
        acc[i][j] = __builtin_amdgcn_mfma_f32_16x16x32_bf16(af[i], bf[j], acc[i][j], 0,0,0);
    __builtin_amdgcn_s_setprio(0);
  }

  #pragma unroll
  for (int i=0;i<4;i++) {
    int rbase = m0 + wr*64 + i*16 + c4*4;
    #pragma unroll
    for (int j=0;j<4;j++) {
      int col = n0 + wc*64 + j*16 + li;
      float bv = bias[col];
      #pragma unroll
      for (int r=0;r<4;r++)
        outF[(size_t)(rbase+r)*1024 + col] = acc[i][j][r] + bv;
    }
  }
}

// ------- causal flash attention: block-staged K/V + cvt_pk/max3 (frozen) ----
__global__ __launch_bounds__(256, 2) void attn_kern(
    const ushort* __restrict__ Qb, const ushort* __restrict__ Kb,
    const ushort* __restrict__ Vt, ushort* __restrict__ Ob)
{
  __shared__ __align__(16) ushort Ks[2][32*68];   // [s][d] stride 68
  __shared__ __align__(16) ushort Vs[2][64*44];   // [dv][s32] stride 44
  __shared__ __align__(16) ushort Pb[4][32*40];   // per-wave P [q][kv]
  __shared__ __align__(16) ushort OT[4][32*72];   // per-wave epilogue transpose
  const int t = threadIdx.x, l = t & 63, w = t >> 6;
  const int bid = blockIdx.x;
  const int x = bid & 7, i0 = bid >> 3;
  const int bh = x*16 + (i0 >> 2);                // bh clustered per XCD
  const int g  = i0 & 3;
  const int p  = g*4 + w;
  const int qta = p, qtb = 31 - p;
  const int NT = 32 - g*4;                        // block-uniform tile count

  const int col = l & 31, hi = l >> 5;
  const ushort* Qp = Qb + (size_t)bh*65536;
  const ushort* Kp = Kb + (size_t)bh*65536;
  const ushort* Vp = Vt + (size_t)bh*65536;

  const int ks_row = t >> 3, ks_c = t & 7;
  const int vs_row = t >> 2, vs_c = t & 3;

  short8 qfa[4], qfb[4];
  #pragma unroll
  for (int m=0;m<4;m++) {
    qfa[m] = *(const short8*)&Qp[(size_t)(qta*32+col)*64 + m*16 + hi*8];
    qfb[m] = *(const short8*)&Qp[(size_t)(qtb*32+col)*64 + m*16 + hi*8];
  }

  f32x16 aA0 = (f32x16)0.0f, aA1 = (f32x16)0.0f;
  f32x16 aB0 = (f32x16)0.0f, aB1 = (f32x16)0.0f;
  float mA = -1e30f, lA = 0.0f, mB = -1e30f, lB = 0.0f;
  ushort* Pw = &Pb[w][0];

  auto PROC = [&](f32x16& s, bool diag, float& mR, float& lS,
                  f32x16& o0, f32x16& o1, const short8* vf0, const short8* vf1) {
    if (diag) {
      #pragma unroll
      for (int r=0;r<16;r++) {
        int kvl = (r&3) + ((r>>2)<<3) + 4*hi;
        s[r] = (kvl > col) ? -1e9f : s[r];
      }
    }
    float t0 = fmaxf(fmaxf(s[0], s[1]), s[2]);
    float t1 = fmaxf(fmaxf(s[3], s[4]), s[5]);
    float t2 = fmaxf(fmaxf(s[6], s[7]), s[8]);
    float t3 = fmaxf(fmaxf(s[9], s[10]), s[11]);
    float t4 = fmaxf(fmaxf(s[12], s[13]), s[14]);
    float mx = fmaxf(fmaxf(fmaxf(t0, t1), t2), fmaxf(fmaxf(t3, t4), s[15]));
    mx = fmaxf(mx, __shfl_xor(mx, 32));
    if (__any(mx - mR > 8.0f)) {          // T13 defer-max (log2 units)
      float mN = fmaxf(mR, mx);
      float corr = __builtin_amdgcn_exp2f(mR - mN);
      mR = mN; lS *= corr;
      #pragma unroll
      for (int r=0;r<16;r++) { o0[r] *= corr; o1[r] *= corr; }
    }
    float pr[16];
    #pragma unroll
    for (int r=0;r<16;r++) pr[r] = __builtin_amdgcn_exp2f(s[r] - mR);
    float s8[8];
    #pragma unroll
    for (int r2=0;r2<8;r2++) s8[r2] = pr[2*r2] + pr[2*r2+1];
    #pragma unroll
    for (int r2=0;r2<4;r2++) s8[r2] += s8[r2+4];
    float rs = (s8[0]+s8[1]) + (s8[2]+s8[3]);
    rs += __shfl_xor(rs, 32);
    lS += rs;
    #pragma unroll
    for (int r2=0;r2<8;r2++) {
      int r = 2*r2;
      int kv = (r&3) + ((r>>2)<<3) + 4*hi;
      *(unsigned*)&Pw[col*40 + kv] = cvtpk(pr[r], pr[r+1]);
    }
    short8 pb0 = *(const short8*)&Pw[col*40 + hi*8];
    short8 pb1 = *(const short8*)&Pw[col*40 + 16 + hi*8];
    o0 = __builtin_amdgcn_mfma_f32_32x32x16_bf16(vf0[0], pb0, o0, 0,0,0);
    o0 = __builtin_amdgcn_mfma_f32_32x32x16_bf16(vf0[1], pb1, o0, 0,0,0);
    o1 = __builtin_amdgcn_mfma_f32_32x32x16_bf16(vf1[0], pb0, o1, 0,0,0);
    o1 = __builtin_amdgcn_mfma_f32_32x32x16_bf16(vf1[1], pb1, o1, 0,0,0);
  };

  { // stage tile 0 into buf 0
    uint4 k0v = *(const uint4*)&Kp[(size_t)ks_row*64 + ks_c*8];
    uint4 v0v = *(const uint4*)&Vp[(size_t)vs_row*1024 + vs_c*8];
    *(uint4*)&Ks[0][ks_row*68 + ks_c*8] = k0v;
    *(uint4*)&Vs[0][vs_row*44 + vs_c*8] = v0v;
  }
  __syncthreads();

  for (int kt = 0; kt < NT; ++kt) {
    const int cur = kt & 1;
    const bool pre = (kt + 1 < NT);
    uint4 kn2, vn2;
    if (pre) {   // T14: global prefetch of tile kt+1 (overlaps PROC below)
      kn2 = *(const uint4*)&Kp[(size_t)((kt+1)*32+ks_row)*64 + ks_c*8];
      vn2 = *(const uint4*)&Vp[(size_t)vs_row*1024 + (kt+1)*32 + vs_c*8];
    }

    short8 kf[4], vf0[2], vf1[2];
    #pragma unroll
    for (int m=0;m<4;m++)
      kf[m] = *(const short8*)&Ks[cur][col*68 + m*16 + hi*8];
    #pragma unroll
    for (int m=0;m<2;m++) {
      vf0[m] = *(const short8*)&Vs[cur][col*44 + m*16 + hi*8];
      vf1[m] = *(const short8*)&Vs[cur][(col+32)*44 + m*16 + hi*8];
    }

    const bool doB = (kt <= qtb), doA = (kt <= qta);
    if (doB) {
      f32x16 sB = (f32x16)0.0f;
      #pragma unroll
      for (int m=0;m<4;m++)
        sB = __builtin_amdgcn_mfma_f32_32x32x16_bf16(kf[m], qfb[m], sB, 0, 0, 0);
      if (doA) {
        f32x16 sA = (f32x16)0.0f;
        #pragma unroll
        for (int m=0;m<4;m++)
          sA = __builtin_amdgcn_mfma_f32_32x32x16_bf16(kf[m], qfa[m], sA, 0, 0, 0);
        PROC(sB, kt == qtb, mB, lB, aB0, aB1, vf0, vf1);
        PROC(sA, kt == qta, mA, lA, aA0, aA1, vf0, vf1);
      } else {
        PROC(sB, kt == qtb, mB, lB, aB0, aB1, vf0, vf1);
      }
    }

    if (pre) {
      *(uint4*)&Ks[cur^1][ks_row*68 + ks_c*8] = kn2;
      *(uint4*)&Vs[cur^1][vs_row*44 + vs_c*8] = vn2;
    }
    __syncthreads();
  }

  // epilogue: O[dv][q] regs -> LDS transpose -> coalesced global store
  const int b = bh >> 4, h = bh & 15;
  auto EPI = [&](int qt, float lS, const f32x16& o0, const f32x16& o1) {
    float inv = 1.0f / lS;
    ushort* o = &OT[w][0];
    #pragma unroll
    for (int r2=0;r2<8;r2++) {
      int r = 2*r2;
      int dv = (r&3) + ((r>>2)<<3) + 4*hi;
      *(unsigned*)&o[col*72 + dv]      = cvtpk(o0[r]*inv, o0[r+1]*inv);
      *(unsigned*)&o[col*72 + 32 + dv] = cvtpk(o1[r]*inv, o1[r+1]*inv);
    }
    #pragma unroll
    for (int it=0; it<4; ++it) {
      int q = it*8 + (l>>3), c8 = (l&7)*8;
      uint4 v = *(const uint4*)&o[q*72 + c8];
      int qg = qt*32 + q;
      *(uint4*)&Ob[(size_t)(b*1024+qg)*1024 + h*64 + c8] = v;
    }
  };
  EPI(qta, lA, aA0, aA1);
  EPI(qtb, lB, aB0, aB1);
}

extern "C" void kernel_launch(void* const* d_in, const int* in_sizes, int n_in,
                              void* d_out, int out_size, void* d_ws, size_t ws_size,
                              hipStream_t stream) {
  const float* query = (const float*)d_in[0];
  const float* Wq = (const float*)d_in[4];
  const float* bq = (const float*)d_in[5];
  const float* Wk = (const float*)d_in[6];
  const float* bk = (const float*)d_in[7];
  const float* Wv = (const float*)d_in[8];
  const float* bv = (const float*)d_in[9];
  const float* Wo = (const float*)d_in[10];
  const float* bo = (const float*)d_in[11];

  char* wsb = (char*)d_ws;
  ushort* Xb   = (ushort*)(wsb);                  // 16 MB
  ushort* Wqkv = (ushort*)(wsb + 16777216);       // 6 MB
  float*  Bqkv = (float*) (wsb + 23068672);       // 12 KB
  ushort* Wob  = (ushort*)(wsb + 23080960);       // 2 MB
  ushort* Qb   = (ushort*)(wsb + 25178112);       // 16 MB
  ushort* Kb   = (ushort*)(wsb + 41955328);       // 16 MB
  ushort* Vtb  = (ushort*)(wsb + 58732544);       // 16 MB  [bh][d][s]
  ushort* Ob   = (ushort*)(wsb + 75509760);       // 16 MB

  hipLaunchKernelGGL(pack_all_kern, dim3(5120), dim3(256), 0, stream,
                     query, Xb, Wq, Wk, Wv, bq, bk, bv, Wo, Wqkv, Bqkv, Wob);
  hipLaunchKernelGGL(gemmw_kern, dim3(768), dim3(256), 0, stream,
                     Xb, Wqkv, Bqkv, Qb, Kb, Vtb);
  hipLaunchKernelGGL(attn_kern, dim3(512), dim3(256), 0, stream, Qb, Kb, Vtb, Ob);
  hipLaunchKernelGGL(gemm128_kern<1>, dim3(512), dim3(256), 0, stream,
                     Ob, Wob, bo, (ushort*)nullptr, (ushort*)nullptr, (ushort*)nullptr,
                     (float*)d_out);
}